// Round 3
// baseline (310.604 us; speedup 1.0000x reference)
//
#include <hip/hip_runtime.h>

#define SEQ 131072
#define DIM 256
#define DTC 0.1f
#define EPSC 1e-8f
#define NT 8            // 64-row tiles per apply block (grid 256 = 1 block/CU)

typedef __attribute__((ext_vector_type(8))) short bf16x8;
typedef __attribute__((ext_vector_type(4))) float f32x4;
typedef __attribute__((ext_vector_type(4))) int   i32x4;
typedef __attribute__((ext_vector_type(4))) unsigned short u16x4;

// f32 -> bf16 round-to-nearest-even (no NaN handling needed: data is bounded)
static __device__ __forceinline__ unsigned short f2bf(float f){
  unsigned int u = __builtin_bit_cast(unsigned int, f);
  u += 0x7fffu + ((u >> 16) & 1u);
  return (unsigned short)(u >> 16);
}

// ---------------------------------------------------------------------------
// Chain stage A (fused k_init + bit4): M1 = I + cH; A = bit4(T) ? M1 : I.
//   cH = -i*s*(Hr + i*Hi) = s*Hi - i*s*Hr,  s = dt/hbar.
// ---------------------------------------------------------------------------
__global__ __launch_bounds__(256)
void k_first(const float* __restrict__ hr, const float* __restrict__ hi,
             const float* __restrict__ hbar, const int* __restrict__ ts,
             float* __restrict__ m1r, float* __restrict__ m1i,
             float* __restrict__ ar,  float* __restrict__ ai)
{
  const int idx = blockIdx.x * 256 + threadIdx.x;   // grid 256 -> 65536
  const int r = idx >> 8, c = idx & 255;
  const float s = DTC / hbar[0];
  const float diag = (r == c) ? 1.0f : 0.0f;
  const float mr = diag + s * hi[idx];
  const float mi =       -s * hr[idx];
  m1r[idx] = mr;  m1i[idx] = mi;
  const bool b = ((ts[0] >> 4) & 1) != 0;
  ar[idx] = b ? mr : diag;
  ai[idx] = b ? mi : 0.0f;
}

// ---------------------------------------------------------------------------
// One square-and-multiply stage:  out = (in*in) * (bit(T,BIT) ? M1 : I)
// Block r computes output row r; both matmuls fused via LDS row buffer.
// ---------------------------------------------------------------------------
template<int BIT>
__global__ __launch_bounds__(256)
void k_step(const float* __restrict__ inr, const float* __restrict__ ini,
            const float* __restrict__ m1r, const float* __restrict__ m1i,
            const int* __restrict__ ts,
            float* __restrict__ outr, float* __restrict__ outi)
{
  __shared__ float rr[256], ri[256], sr[256], si[256];
  const int r = blockIdx.x, c = threadIdx.x;
  rr[c] = inr[r*256 + c];
  ri[c] = ini[r*256 + c];
  __syncthreads();

  float ar = 0.f, ai = 0.f;
  #pragma unroll 8
  for (int k = 0; k < 256; ++k){
    const float br = inr[k*256 + c], bi = ini[k*256 + c];  // coalesced across c
    const float xr = rr[k],          xi = ri[k];           // LDS broadcast
    ar = fmaf(xr, br, fmaf(-xi, bi, ar));
    ai = fmaf(xr, bi, fmaf( xi, br, ai));
  }

  const bool bit = ((ts[0] >> BIT) & 1) != 0;   // block-uniform branch
  if (!bit){
    outr[r*256 + c] = ar; outi[r*256 + c] = ai;
    return;
  }
  sr[c] = ar; si[c] = ai;
  __syncthreads();
  float orr = 0.f, oii = 0.f;
  #pragma unroll 8
  for (int k = 0; k < 256; ++k){
    const float br = m1r[k*256 + c], bi = m1i[k*256 + c];
    const float xr = sr[k],          xi = si[k];
    orr = fmaf(xr, br, fmaf(-xi, bi, orr));
    oii = fmaf(xr, bi, fmaf( xi, br, oii));
  }
  outr[r*256 + c] = orr; outi[r*256 + c] = oii;
}

// ---------------------------------------------------------------------------
// Chain stage Z (fused bit0 + frag emission): out = in^2 * (bit0 ? M1 : I);
// also scatters bf16 B-fragments of R = out - I in apply's per-thread layout.
//   element P[r][c] -> R[C=r][K=c]:
//   ftid = (C>>5)*64 + ((K>>3)&3)*16 + (C&15);  fid = (((C>>4)&1)*8 + (K>>5))*2
// ---------------------------------------------------------------------------
__global__ __launch_bounds__(256)
void k_last(const float* __restrict__ inr, const float* __restrict__ ini,
            const float* __restrict__ m1r, const float* __restrict__ m1i,
            const int* __restrict__ ts,
            float* __restrict__ outr, float* __restrict__ outi,
            unsigned short* __restrict__ fragbuf)
{
  __shared__ float rr[256], ri[256], sr[256], si[256];
  const int r = blockIdx.x, c = threadIdx.x;
  rr[c] = inr[r*256 + c];
  ri[c] = ini[r*256 + c];
  __syncthreads();

  float ar = 0.f, ai = 0.f;
  #pragma unroll 8
  for (int k = 0; k < 256; ++k){
    const float br = inr[k*256 + c], bi = ini[k*256 + c];
    const float xr = rr[k],          xi = ri[k];
    ar = fmaf(xr, br, fmaf(-xi, bi, ar));
    ai = fmaf(xr, bi, fmaf( xi, br, ai));
  }

  float orr, oii;
  const bool bit = (ts[0] & 1) != 0;   // block-uniform
  if (bit){
    sr[c] = ar; si[c] = ai;
    __syncthreads();
    orr = 0.f; oii = 0.f;
    #pragma unroll 8
    for (int k = 0; k < 256; ++k){
      const float br = m1r[k*256 + c], bi = m1i[k*256 + c];
      const float xr = sr[k],          xi = si[k];
      orr = fmaf(xr, br, fmaf(-xi, bi, orr));
      oii = fmaf(xr, bi, fmaf( xi, br, oii));
    }
  } else { orr = ar; oii = ai; }

  outr[r*256 + c] = orr;
  outi[r*256 + c] = oii;

  if (fragbuf){
    const int C = r, K = c;
    const int ftid = (C>>5)*64 + ((K>>3)&3)*16 + (C&15);
    const int fid  = (((C>>4)&1)*8 + (K>>5))*2;
    fragbuf[((size_t)fid*512     + ftid)*8 + (K&7)] = f2bf(orr - ((r==c)?1.0f:0.0f));
    fragbuf[((size_t)(fid+1)*512 + ftid)*8 + (K&7)] = f2bf(oii);
  }
}

// ---------------------------------------------------------------------------
// Main apply, pipelined: grid 256 (1 block/CU), NT=8 tiles of 64 rows each.
// out = normalize_rows( q + q @ R^T ),  R = M^T_power - I  (f32 residual).
// LDS snapshot XOR-swizzled: byte(row,col) = row*512 + ((col*2)^((row&7)<<4)).
// Per tile: [convert+LDS write | sync | prefetch next tile | 4x(MFMA phase,
// residual re-read from L2, partials, sync, scale+store)].
// ---------------------------------------------------------------------------
template<int STORE_COMPLEX>
__global__ __launch_bounds__(512, 2)
void apply2(const float* __restrict__ psi_re, const float* __restrict__ psi_im,
            const unsigned short* __restrict__ fragbuf,
            const int* __restrict__ tsteps, float* __restrict__ out)
{
  __shared__ alignas(16) unsigned short a_re[64*256];
  __shared__ alignas(16) unsigned short a_im[64*256];
  __shared__ float partials[64][8];

  const int tid  = threadIdx.x;
  const int wv   = tid >> 6;
  const int lane = tid & 63;
  const int lq   = lane >> 4;
  const int lr   = lane & 15;
  const int cbase = wv << 5;
  const int T = tsteps[0];

  // ---- persistent B fragments (R = P - I), fully coalesced ----
  bf16x8 bhr[2][8], bhi[2][8];
  {
    const bf16x8* fb = reinterpret_cast<const bf16x8*>(fragbuf);
    #pragma unroll
    for (int ct = 0; ct < 2; ++ct)
      #pragma unroll
      for (int kt = 0; kt < 8; ++kt){
        bhr[ct][kt] = fb[((ct*8 + kt)*2 + 0)*512 + tid];   // 1 KB/wave-inst
        bhi[ct][kt] = fb[((ct*8 + kt)*2 + 1)*512 + tid];
      }
  }

  const size_t block_base = (size_t)blockIdx.x * NT * (64*256);

  // ---- prologue: stage tile 0 (linear layout: row j*8+wv, cols lane*4..+3) --
  float4 str[8], sti[8];
  #pragma unroll
  for (int j = 0; j < 8; ++j){
    str[j] = *reinterpret_cast<const float4*>(&psi_re[block_base + j*2048 + tid*4]);
    sti[j] = *reinterpret_cast<const float4*>(&psi_im[block_base + j*2048 + tid*4]);
  }

  for (int t = 0; t < NT; ++t){
    // ---- convert + swizzled LDS snapshot (row-contiguous b64, conflict-free)
    {
      const int wb = (lane << 3) ^ (wv << 4);   // row&7 == wv for row=j*8+wv
      #pragma unroll
      for (int j = 0; j < 8; ++j){
        const int row = j*8 + wv;
        u16x4 pr, pi_;
        pr[0]=f2bf(str[j].x); pr[1]=f2bf(str[j].y); pr[2]=f2bf(str[j].z); pr[3]=f2bf(str[j].w);
        pi_[0]=f2bf(sti[j].x); pi_[1]=f2bf(sti[j].y); pi_[2]=f2bf(sti[j].z); pi_[3]=f2bf(sti[j].w);
        *reinterpret_cast<u16x4*>(reinterpret_cast<char*>(a_re) + row*512 + wb) = pr;
        *reinterpret_cast<u16x4*>(reinterpret_cast<char*>(a_im) + row*512 + wb) = pi_;
      }
    }
    __syncthreads();

    // ---- prefetch next tile into staging regs (hidden under MFMA phases) ----
    if (t + 1 < NT){
      const size_t nb = block_base + (size_t)(t+1)*(64*256);
      #pragma unroll
      for (int j = 0; j < 8; ++j){
        str[j] = *reinterpret_cast<const float4*>(&psi_re[nb + j*2048 + tid*4]);
        sti[j] = *reinterpret_cast<const float4*>(&psi_im[nb + j*2048 + tid*4]);
      }
    }

    const int trow = (blockIdx.x*NT + t) * 64;

    #pragma unroll
    for (int rt = 0; rt < 4; ++rt){
      // residual f32 re-read (L2/LLC-hot; exact f32 precision preserved)
      float qr0[4], qi0[4], qr1[4], qi1[4];
      #pragma unroll
      for (int j = 0; j < 4; ++j){
        const size_t off = (size_t)(trow + rt*16 + lq*4 + j)*DIM + cbase + lr;
        qr0[j] = psi_re[off];      qi0[j] = psi_im[off];
        qr1[j] = psi_re[off+16];   qi1[j] = psi_im[off+16];
      }

      f32x4 ar0 = {0.f,0.f,0.f,0.f}, ar1 = {0.f,0.f,0.f,0.f};
      f32x4 ai0 = {0.f,0.f,0.f,0.f}, ai1 = {0.f,0.f,0.f,0.f};
      const int rb = (rt*16 + lr) * 512;     // A-frag row byte base
      const int sm = (lr & 7) << 4;          // read-side swizzle mask
      #pragma unroll
      for (int kt = 0; kt < 8; ++kt){
        const int xo = ((kt<<6) + (lq<<4)) ^ sm;
        bf16x8 apr = *reinterpret_cast<const bf16x8*>(reinterpret_cast<const char*>(a_re) + rb + xo);
        bf16x8 api = *reinterpret_cast<const bf16x8*>(reinterpret_cast<const char*>(a_im) + rb + xo);
        i32x4 tneg = __builtin_bit_cast(i32x4, api) ^ (i32x4)(int)0x80008000;
        bf16x8 apin = __builtin_bit_cast(bf16x8, tneg);   // -qi (bf16 sign flip)
        // g_re = qr@Rr - qi@Ri ; g_im = qr@Ri + qi@Rr
        ar0 = __builtin_amdgcn_mfma_f32_16x16x32_bf16(apr,  bhr[0][kt], ar0, 0,0,0);
        ai0 = __builtin_amdgcn_mfma_f32_16x16x32_bf16(apr,  bhi[0][kt], ai0, 0,0,0);
        ar1 = __builtin_amdgcn_mfma_f32_16x16x32_bf16(apr,  bhr[1][kt], ar1, 0,0,0);
        ai1 = __builtin_amdgcn_mfma_f32_16x16x32_bf16(apr,  bhi[1][kt], ai1, 0,0,0);
        ar0 = __builtin_amdgcn_mfma_f32_16x16x32_bf16(apin, bhi[0][kt], ar0, 0,0,0);
        ai0 = __builtin_amdgcn_mfma_f32_16x16x32_bf16(api,  bhr[0][kt], ai0, 0,0,0);
        ar1 = __builtin_amdgcn_mfma_f32_16x16x32_bf16(apin, bhi[1][kt], ar1, 0,0,0);
        ai1 = __builtin_amdgcn_mfma_f32_16x16x32_bf16(api,  bhr[1][kt], ai1, 0,0,0);
      }

      // out = q + g (in place); row-norm partials via 16-lane butterfly
      #pragma unroll
      for (int j = 0; j < 4; ++j){
        qr0[j] += ar0[j];  qi0[j] += ai0[j];
        qr1[j] += ar1[j];  qi1[j] += ai1[j];
        float v = qr0[j]*qr0[j] + qi0[j]*qi0[j] + qr1[j]*qr1[j] + qi1[j]*qi1[j];
        v += __shfl_xor(v, 1);
        v += __shfl_xor(v, 2);
        v += __shfl_xor(v, 4);
        v += __shfl_xor(v, 8);
        if (lr == 0) partials[rt*16 + lq*4 + j][wv] = v;
      }
      __syncthreads();

      // scale + store (broadcast partials reads; all lanes active)
      #pragma unroll
      for (int j = 0; j < 4; ++j){
        const int rl = rt*16 + lq*4 + j;
        const f32x4 p0 = *reinterpret_cast<const f32x4*>(&partials[rl][0]);
        const f32x4 p1 = *reinterpret_cast<const f32x4*>(&partials[rl][4]);
        const float nrm = ((p0[0]+p0[1]) + (p0[2]+p0[3]))
                        + ((p1[0]+p1[1]) + (p1[2]+p1[3]));
        const float sc = (T == 0) ? 1.0f : 1.0f/(sqrtf(nrm) + EPSC);
        const size_t off = (size_t)(trow + rl)*DIM + cbase + lr;
        if (STORE_COMPLEX){
          float2 v0 = {qr0[j]*sc, qi0[j]*sc};
          float2 v1 = {qr1[j]*sc, qi1[j]*sc};
          *reinterpret_cast<float2*>(&out[off*2])      = v0;
          *reinterpret_cast<float2*>(&out[(off+16)*2]) = v1;
        } else {
          out[off]    = qr0[j]*sc;
          out[off+16] = qr1[j]*sc;
        }
      }
    }
  }
}

// ---------------------------------------------------------------------------
// Fallback A: single-tile apply reading Pre/Pim inline (ws fits matrices only).
// ---------------------------------------------------------------------------
template<int STORE_COMPLEX>
__global__ __launch_bounds__(512, 2)
void apply_kernel(const float* __restrict__ psi_re, const float* __restrict__ psi_im,
                  const float* __restrict__ Pre,    const float* __restrict__ Pim,
                  const int* __restrict__ tsteps,   float* __restrict__ out)
{
  __shared__ alignas(16) unsigned short a_re[64][272];
  __shared__ alignas(16) unsigned short a_im[64][272];
  __shared__ float partials[64][8];
  __shared__ float scales[64];

  const int tid  = threadIdx.x;
  const int wv   = tid >> 6;
  const int lane = tid & 63;
  const int lq   = lane >> 4;
  const int lr   = lane & 15;
  const int brow = blockIdx.x << 6;
  const int cbase = wv << 5;
  const int T = tsteps[0];

  bf16x8 bhr[2][8], bhi[2][8];
  #pragma unroll
  for (int ct = 0; ct < 2; ++ct){
    const int c = cbase + ct*16 + lr;
    #pragma unroll
    for (int kt = 0; kt < 8; ++kt){
      const int kb = kt*32 + lq*8;
      const float4 pr0 = *reinterpret_cast<const float4*>(&Pre[c*DIM + kb]);
      const float4 pr1 = *reinterpret_cast<const float4*>(&Pre[c*DIM + kb + 4]);
      const float4 pi0 = *reinterpret_cast<const float4*>(&Pim[c*DIM + kb]);
      const float4 pi1 = *reinterpret_cast<const float4*>(&Pim[c*DIM + kb + 4]);
      const float re8[8] = {pr0.x,pr0.y,pr0.z,pr0.w, pr1.x,pr1.y,pr1.z,pr1.w};
      const float im8[8] = {pi0.x,pi0.y,pi0.z,pi0.w, pi1.x,pi1.y,pi1.z,pi1.w};
      bf16x8 vr, vi;
      #pragma unroll
      for (int i = 0; i < 8; ++i){
        const float rv = re8[i] - ((c == kb + i) ? 1.0f : 0.0f);
        vr[i] = (short)f2bf(rv);
        vi[i] = (short)f2bf(im8[i]);
      }
      bhr[ct][kt] = vr; bhi[ct][kt] = vi;
    }
  }

  float sre[4][2][4], simg[4][2][4];
  #pragma unroll
  for (int rt = 0; rt < 4; ++rt)
    #pragma unroll
    for (int ct = 0; ct < 2; ++ct)
      #pragma unroll
      for (int j = 0; j < 4; ++j){
        const int row = brow + rt*16 + lq*4 + j;
        const int col = cbase + ct*16 + lr;
        const float xr = psi_re[row*DIM + col];
        const float xi = psi_im[row*DIM + col];
        sre [rt][ct][j] = xr;
        simg[rt][ct][j] = xi;
        a_re[rt*16 + lq*4 + j][col] = f2bf(xr);
        a_im[rt*16 + lq*4 + j][col] = f2bf(xi);
      }
  __syncthreads();

  #pragma unroll
  for (int rt = 0; rt < 4; ++rt){
    f32x4 ar0 = {0.f,0.f,0.f,0.f}, ar1 = {0.f,0.f,0.f,0.f};
    f32x4 ai0 = {0.f,0.f,0.f,0.f}, ai1 = {0.f,0.f,0.f,0.f};
    #pragma unroll
    for (int kt = 0; kt < 8; ++kt){
      const int arow = rt*16 + lr;
      const int kofs = kt*32 + lq*8;
      bf16x8 apr = *reinterpret_cast<const bf16x8*>(&a_re[arow][kofs]);
      bf16x8 api = *reinterpret_cast<const bf16x8*>(&a_im[arow][kofs]);
      i32x4 tneg = __builtin_bit_cast(i32x4, api) ^ (i32x4)(int)0x80008000;
      bf16x8 apin = __builtin_bit_cast(bf16x8, tneg);
      ar0 = __builtin_amdgcn_mfma_f32_16x16x32_bf16(apr,  bhr[0][kt], ar0, 0,0,0);
      ai0 = __builtin_amdgcn_mfma_f32_16x16x32_bf16(apr,  bhi[0][kt], ai0, 0,0,0);
      ar1 = __builtin_amdgcn_mfma_f32_16x16x32_bf16(apr,  bhr[1][kt], ar1, 0,0,0);
      ai1 = __builtin_amdgcn_mfma_f32_16x16x32_bf16(apr,  bhi[1][kt], ai1, 0,0,0);
      ar0 = __builtin_amdgcn_mfma_f32_16x16x32_bf16(apin, bhi[0][kt], ar0, 0,0,0);
      ai0 = __builtin_amdgcn_mfma_f32_16x16x32_bf16(api,  bhr[0][kt], ai0, 0,0,0);
      ar1 = __builtin_amdgcn_mfma_f32_16x16x32_bf16(apin, bhi[1][kt], ar1, 0,0,0);
      ai1 = __builtin_amdgcn_mfma_f32_16x16x32_bf16(api,  bhr[1][kt], ai1, 0,0,0);
    }
    float ss[4];
    #pragma unroll
    for (int j = 0; j < 4; ++j){
      sre [rt][0][j] += ar0[j];
      simg[rt][0][j] += ai0[j];
      sre [rt][1][j] += ar1[j];
      simg[rt][1][j] += ai1[j];
      float v = sre[rt][0][j]*sre[rt][0][j] + simg[rt][0][j]*simg[rt][0][j]
              + sre[rt][1][j]*sre[rt][1][j] + simg[rt][1][j]*simg[rt][1][j];
      v += __shfl_xor(v, 1);
      v += __shfl_xor(v, 2);
      v += __shfl_xor(v, 4);
      v += __shfl_xor(v, 8);
      ss[j] = v;
    }
    if (lr == 0){
      #pragma unroll
      for (int j = 0; j < 4; ++j)
        partials[rt*16 + lq*4 + j][wv] = ss[j];
    }
  }
  __syncthreads();

  if (tid < 64){
    float acc = 0.f;
    #pragma unroll
    for (int w = 0; w < 8; ++w) acc += partials[tid][w];
    scales[tid] = (T == 0) ? 1.0f : 1.0f / (sqrtf(acc) + EPSC);
  }
  __syncthreads();

  #pragma unroll
  for (int rt = 0; rt < 4; ++rt)
    #pragma unroll
    for (int ct = 0; ct < 2; ++ct)
      #pragma unroll
      for (int j = 0; j < 4; ++j){
        const int row = brow + rt*16 + lq*4 + j;
        const int col = cbase + ct*16 + lr;
        const float sc = scales[rt*16 + lq*4 + j];
        const float xr = sre [rt][ct][j] * sc;
        const float xi = simg[rt][ct][j] * sc;
        if (STORE_COMPLEX){
          float2 v2 = {xr, xi};
          *reinterpret_cast<float2*>(&out[(size_t)(row*DIM + col)*2]) = v2;
        } else {
          out[row*DIM + col] = xr;
        }
      }
}

// ---------------------------------------------------------------------------
// Fallback B: original verified 10-step kernel (used only if ws too small).
// ---------------------------------------------------------------------------
template<int STORE_COMPLEX>
__global__ __launch_bounds__(512, 2)
void qevolve_kernel(const float* __restrict__ psi_re, const float* __restrict__ psi_im,
                    const float* __restrict__ ham_re, const float* __restrict__ ham_im,
                    const float* __restrict__ hbar,   const int* __restrict__ tsteps,
                    float* __restrict__ out)
{
  __shared__ alignas(16) unsigned short a_re[64][272];
  __shared__ alignas(16) unsigned short a_im[64][272];
  __shared__ float partials[64][8];
  __shared__ float scales[64];

  const int tid  = threadIdx.x;
  const int wv   = tid >> 6;
  const int lane = tid & 63;
  const int lq   = lane >> 4;
  const int lr   = lane & 15;
  const int brow = blockIdx.x << 6;
  const int cbase = wv << 5;
  const float cs = DTC / hbar[0];
  const int T = tsteps[0];

  bf16x8 bhr[2][8], bhi[2][8];
  #pragma unroll
  for (int ct = 0; ct < 2; ++ct){
    const int c = cbase + ct*16 + lr;
    #pragma unroll
    for (int kt = 0; kt < 8; ++kt){
      const int kb = kt*32 + lq*8;
      bf16x8 vr, vi;
      #pragma unroll
      for (int i = 0; i < 8; ++i){
        vr[i] = (short)f2bf(ham_re[c*DIM + kb + i]);
        vi[i] = (short)f2bf(ham_im[c*DIM + kb + i]);
      }
      bhr[ct][kt] = vr; bhi[ct][kt] = vi;
    }
  }

  float sre[4][2][4], simg[4][2][4];
  #pragma unroll
  for (int rt = 0; rt < 4; ++rt)
    #pragma unroll
    for (int ct = 0; ct < 2; ++ct)
      #pragma unroll
      for (int j = 0; j < 4; ++j){
        const int row = brow + rt*16 + lq*4 + j;
        const int col = cbase + ct*16 + lr;
        sre [rt][ct][j] = psi_re[row*DIM + col];
        simg[rt][ct][j] = psi_im[row*DIM + col];
      }

  for (int s = 0; s < T; ++s){
    #pragma unroll
    for (int rt = 0; rt < 4; ++rt)
      #pragma unroll
      for (int ct = 0; ct < 2; ++ct)
        #pragma unroll
        for (int j = 0; j < 4; ++j){
          const int row = rt*16 + lq*4 + j;
          const int col = cbase + ct*16 + lr;
          a_re[row][col] = f2bf(sre [rt][ct][j]);
          a_im[row][col] = f2bf(simg[rt][ct][j]);
        }
    __syncthreads();

    #pragma unroll
    for (int rt = 0; rt < 4; ++rt){
      f32x4 ar0 = {0.f,0.f,0.f,0.f}, ar1 = {0.f,0.f,0.f,0.f};
      f32x4 ai0 = {0.f,0.f,0.f,0.f}, ai1 = {0.f,0.f,0.f,0.f};
      #pragma unroll
      for (int kt = 0; kt < 8; ++kt){
        const int arow = rt*16 + lr;
        const int kofs = kt*32 + lq*8;
        bf16x8 apr = *reinterpret_cast<const bf16x8*>(&a_re[arow][kofs]);
        bf16x8 api = *reinterpret_cast<const bf16x8*>(&a_im[arow][kofs]);
        i32x4 tneg = __builtin_bit_cast(i32x4, api) ^ (i32x4)(int)0x80008000;
        bf16x8 apin = __builtin_bit_cast(bf16x8, tneg);
        ar0 = __builtin_amdgcn_mfma_f32_16x16x32_bf16(apr,  bhr[0][kt], ar0, 0,0,0);
        ai0 = __builtin_amdgcn_mfma_f32_16x16x32_bf16(apr,  bhi[0][kt], ai0, 0,0,0);
        ar1 = __builtin_amdgcn_mfma_f32_16x16x32_bf16(apr,  bhr[1][kt], ar1, 0,0,0);
        ai1 = __builtin_amdgcn_mfma_f32_16x16x32_bf16(apr,  bhi[1][kt], ai1, 0,0,0);
        ar0 = __builtin_amdgcn_mfma_f32_16x16x32_bf16(apin, bhi[0][kt], ar0, 0,0,0);
        ai0 = __builtin_amdgcn_mfma_f32_16x16x32_bf16(api,  bhr[0][kt], ai0, 0,0,0);
        ar1 = __builtin_amdgcn_mfma_f32_16x16x32_bf16(apin, bhi[1][kt], ar1, 0,0,0);
        ai1 = __builtin_amdgcn_mfma_f32_16x16x32_bf16(api,  bhr[1][kt], ai1, 0,0,0);
      }
      float ss[4];
      #pragma unroll
      for (int j = 0; j < 4; ++j){
        sre [rt][0][j] += cs * ai0[j];
        simg[rt][0][j] -= cs * ar0[j];
        sre [rt][1][j] += cs * ai1[j];
        simg[rt][1][j] -= cs * ar1[j];
        float v = sre[rt][0][j]*sre[rt][0][j] + simg[rt][0][j]*simg[rt][0][j]
                + sre[rt][1][j]*sre[rt][1][j] + simg[rt][1][j]*simg[rt][1][j];
        v += __shfl_xor(v, 1);
        v += __shfl_xor(v, 2);
        v += __shfl_xor(v, 4);
        v += __shfl_xor(v, 8);
        ss[j] = v;
      }
      if (lr == 0){
        #pragma unroll
        for (int j = 0; j < 4; ++j)
          partials[rt*16 + lq*4 + j][wv] = ss[j];
      }
    }
    __syncthreads();

    if (tid < 64){
      float acc = 0.f;
      #pragma unroll
      for (int w = 0; w < 8; ++w) acc += partials[tid][w];
      scales[tid] = 1.0f / (sqrtf(acc) + EPSC);
    }
    __syncthreads();

    #pragma unroll
    for (int rt = 0; rt < 4; ++rt)
      #pragma unroll
      for (int j = 0; j < 4; ++j){
        const float sc = scales[rt*16 + lq*4 + j];
        sre [rt][0][j] *= sc; sre [rt][1][j] *= sc;
        simg[rt][0][j] *= sc; simg[rt][1][j] *= sc;
      }
  }

  #pragma unroll
  for (int rt = 0; rt < 4; ++rt)
    #pragma unroll
    for (int ct = 0; ct < 2; ++ct)
      #pragma unroll
      for (int j = 0; j < 4; ++j){
        const int row = brow + rt*16 + lq*4 + j;
        const int col = cbase + ct*16 + lr;
        if (STORE_COMPLEX){
          out[(size_t)(row*DIM + col)*2 + 0] = sre [rt][ct][j];
          out[(size_t)(row*DIM + col)*2 + 1] = simg[rt][ct][j];
        } else {
          out[row*DIM + col] = sre[rt][ct][j];
        }
      }
}

extern "C" void kernel_launch(void* const* d_in, const int* in_sizes, int n_in,
                              void* d_out, int out_size, void* d_ws, size_t ws_size,
                              hipStream_t stream)
{
  const float* psi_re = (const float*)d_in[0];
  const float* psi_im = (const float*)d_in[1];
  const float* ham_re = (const float*)d_in[2];
  const float* ham_im = (const float*)d_in[3];
  const float* hbar   = (const float*)d_in[4];
  const int*   tstep  = (const int*)d_in[5];
  float* out = (float*)d_out;

  const size_t NMAT    = (size_t)DIM * DIM;             // 65536
  const size_t WS_MAT  = 6 * NMAT * sizeof(float);      // 1.5 MB
  const size_t WS_FRAG = 2 * 8 * 2 * 512 * 16;          // 256 KB (bf16x8 frags)

  const bool cplx = (out_size == 2 * SEQ * DIM);

  if (d_ws != nullptr && ws_size >= WS_MAT){
    float* w   = (float*)d_ws;
    float* m1r = w + 0*NMAT; float* m1i = w + 1*NMAT;
    float* Ar  = w + 2*NMAT; float* Ai  = w + 3*NMAT;
    float* Br  = w + 4*NMAT; float* Bi  = w + 5*NMAT;
    const bool have_frag = (ws_size >= WS_MAT + WS_FRAG);
    unsigned short* fragbuf = have_frag ? (unsigned short*)(w + 6*NMAT) : nullptr;

    // P = (I + cH)^T_power via square-and-multiply, 5 bits (T <= 31), 5 launches.
    k_first  <<<256, 256, 0, stream>>>(ham_re, ham_im, hbar, tstep, m1r, m1i, Ar, Ai);
    k_step<3><<<256, 256, 0, stream>>>(Ar, Ai, m1r, m1i, tstep, Br, Bi);
    k_step<2><<<256, 256, 0, stream>>>(Br, Bi, m1r, m1i, tstep, Ar, Ai);
    k_step<1><<<256, 256, 0, stream>>>(Ar, Ai, m1r, m1i, tstep, Br, Bi);
    k_last   <<<256, 256, 0, stream>>>(Br, Bi, m1r, m1i, tstep, Ar, Ai, fragbuf);
    // final P in (Ar, Ai); bf16 fragments of R = P - I in fragbuf

    if (have_frag){
      dim3 grid(SEQ / 64 / NT), block(512);     // 256 blocks = 1/CU, 8 tiles each
      if (cplx)
        apply2<1><<<grid, block, 0, stream>>>(psi_re, psi_im, fragbuf, tstep, out);
      else
        apply2<0><<<grid, block, 0, stream>>>(psi_re, psi_im, fragbuf, tstep, out);
    } else {
      dim3 grid(SEQ / 64), block(512);
      if (cplx)
        apply_kernel<1><<<grid, block, 0, stream>>>(psi_re, psi_im, Ar, Ai, tstep, out);
      else
        apply_kernel<0><<<grid, block, 0, stream>>>(psi_re, psi_im, Ar, Ai, tstep, out);
    }
  } else {
    dim3 grid(SEQ / 64), block(512);
    if (cplx)
      qevolve_kernel<1><<<grid, block, 0, stream>>>(psi_re, psi_im, ham_re, ham_im, hbar, tstep, out);
    else
      qevolve_kernel<0><<<grid, block, 0, stream>>>(psi_re, psi_im, ham_re, ham_im, hbar, tstep, out);
  }

  (void)in_sizes; (void)n_in;
}